// Round 3
// baseline (1834.389 us; speedup 1.0000x reference)
//
#include <hip/hip_runtime.h>

// B=128 trajectories, N=20000 vars, M=85400 clauses, K=3 literals/clause.
// Inputs: v(B*N) f32, xl(B*M) f32, xs(B*M) f32, param(6) f32,
//         input_sign(B*M*K) f32, input_idx(B*M*K) i32
// Outputs concat: C(B*M), grad_v(B*N), dxl(B*M), dxs(B*M)  -- all f32

#define NMAX 20000     // sv only: 80KB LDS -> 2 blocks/CU = 32 waves (R2 was 16)
#define BPB  4         // blocks per batch element -> grid 512 = 2 blocks/CU

// native clang vector types — required by __builtin_nontemporal_load/store
typedef int   int4v   __attribute__((ext_vector_type(4)));
typedef float float4v __attribute__((ext_vector_type(4)));

__device__ __forceinline__ void clause_math(
    float a0, float a1, float a2, float xlv, float xsv, float zeta,
    float& C, float& g0, float& g1, float& g2)
{
    // top-2 with jax.lax.top_k tie semantics (first occurrence wins argmax)
    int k0; float m0, m1;
    if (a0 >= a1) {
        if (a0 >= a2) { k0 = 0; m0 = a0; m1 = fmaxf(a1, a2); }
        else          { k0 = 2; m0 = a2; m1 = fmaxf(a0, a1); }
    } else {
        if (a1 >= a2) { k0 = 1; m0 = a1; m1 = fmaxf(a0, a2); }
        else          { k0 = 2; m0 = a2; m1 = fmaxf(a0, a1); }
    }
    C = (1.f - m0) * 0.5f;
    const float T2 = (1.f - m1) * 0.5f;
    const float gl = xlv * xsv;
    const float rC = C * ((1.f + zeta * xlv) * (1.f - xsv));
    g0 = (k0 == 0 ? T2 : C) * gl + (k0 == 0 ? rC : 0.f);
    g1 = (k0 == 1 ? T2 : C) * gl + (k0 == 1 ? rC : 0.f);
    g2 = (k0 == 2 ? T2 : C) * gl + (k0 == 2 ? rC : 0.f);
}

// ---------- fast path: v in LDS (gathers, R1 lesson), grad via L2 atomics ----------
// 80KB LDS -> 2 blocks/CU -> 32 waves for latency hiding of streaming loads.
__global__ __launch_bounds__(1024, 8) void or_priv5(
    const float* __restrict__ v,
    const float* __restrict__ xl,
    const float* __restrict__ xs,
    const float* __restrict__ param,
    const float* __restrict__ sign,
    const int*   __restrict__ idx,
    float* __restrict__ outC,
    float* __restrict__ outdxl,
    float* __restrict__ outdxs,
    float* __restrict__ gradv,    // pre-zeroed; fire-and-forget f32 atomics
    int N, int M, int B, int chunk)
{
    __shared__ float sv[NMAX];   // v slice for batch b

    // XCD swizzle: the BPB=4 blocks of each b land on ONE XCD -> v-stage re-reads
    // and all grad atomics for b stay in that XCD's L2. grid=512, multiple of 8.
    const int id  = blockIdx.x;
    const int cpx = gridDim.x >> 3;
    const int cid = ((gridDim.x & 7) == 0) ? ((id & 7) * cpx + (id >> 3)) : id;
    const int b   = cid >> 2;              // BPB == 4
    const int j   = cid & 3;
    const int tid = threadIdx.x;

    // stage v slice (coalesced float4, cached — later blocks of the quad hit L2)
    {
        const float4v* __restrict__ v4 = (const float4v*)(v + (size_t)b * N);
        float4v* sv4 = (float4v*)sv;
        const int n4 = N >> 2;
        for (int i = tid; i < n4; i += 1024) sv4[i] = v4[i];
        for (int i = (n4 << 2) + tid; i < N; i += 1024)
            sv[i] = v[(size_t)b * N + i];
    }
    __syncthreads();

    const float alpha = param[0], beta = param[1], gamma = param[2];
    const float delta = param[3], eps  = param[4], zeta  = param[5];

    float* __restrict__ gb = gradv + (size_t)b * N;

    const int mstart = j * chunk;                 // chunk is a multiple of 4
    const int mend   = min(M, mstart + chunk);
    const int mlen   = mend - mstart;

    if (mlen > 0 && (mlen & 3) == 0) {
        const int ngroups = mlen >> 2;
        int g = tid;
        int4v   ia = {}, ib = {}, ic = {};
        float4v sa = {}, sb = {}, sc = {}, xl4 = {}, xs4 = {};
        if (g < ngroups) {
            const size_t base = (size_t)b * M + mstart + ((size_t)g << 2);
            const int4v*   __restrict__ ip = (const int4v*)(idx + base * 3);
            const float4v* __restrict__ sp = (const float4v*)(sign + base * 3);
            ia = __builtin_nontemporal_load(ip + 0);
            ib = __builtin_nontemporal_load(ip + 1);
            ic = __builtin_nontemporal_load(ip + 2);
            sa = __builtin_nontemporal_load(sp + 0);
            sb = __builtin_nontemporal_load(sp + 1);
            sc = __builtin_nontemporal_load(sp + 2);
            xl4 = __builtin_nontemporal_load((const float4v*)(xl + base));
            xs4 = __builtin_nontemporal_load((const float4v*)(xs + base));
        }
        for (; g < ngroups; g += 1024) {
            const int gn = g + 1024;
            int4v   ia2 = {}, ib2 = {}, ic2 = {};
            float4v sa2 = {}, sb2 = {}, sc2 = {}, xl42 = {}, xs42 = {};
            if (gn < ngroups) {
                const size_t basen = (size_t)b * M + mstart + ((size_t)gn << 2);
                const int4v*   __restrict__ ipn = (const int4v*)(idx + basen * 3);
                const float4v* __restrict__ spn = (const float4v*)(sign + basen * 3);
                ia2 = __builtin_nontemporal_load(ipn + 0);
                ib2 = __builtin_nontemporal_load(ipn + 1);
                ic2 = __builtin_nontemporal_load(ipn + 2);
                sa2 = __builtin_nontemporal_load(spn + 0);
                sb2 = __builtin_nontemporal_load(spn + 1);
                sc2 = __builtin_nontemporal_load(spn + 2);
                xl42 = __builtin_nontemporal_load((const float4v*)(xl + basen));
                xs42 = __builtin_nontemporal_load((const float4v*)(xs + basen));
            }

            const size_t base = (size_t)b * M + mstart + ((size_t)g << 2);
            const int   ii[12] = {ia.x, ia.y, ia.z, ia.w, ib.x, ib.y, ib.z, ib.w,
                                  ic.x, ic.y, ic.z, ic.w};
            const float ss[12] = {sa.x, sa.y, sa.z, sa.w, sb.x, sb.y, sb.z, sb.w,
                                  sc.x, sc.y, sc.z, sc.w};
            const float xlA[4] = {xl4.x, xl4.y, xl4.z, xl4.w};
            const float xsA[4] = {xs4.x, xs4.y, xs4.z, xs4.w};
            float Cv[4], dxlv[4], dxsv[4];

            #pragma unroll
            for (int c = 0; c < 4; ++c) {
                const int   i0 = ii[3*c], i1 = ii[3*c+1], i2 = ii[3*c+2];
                const float s0 = ss[3*c], s1 = ss[3*c+1], s2 = ss[3*c+2];
                const float a0 = sv[i0] * s0, a1 = sv[i1] * s1, a2 = sv[i2] * s2;
                float C, g0, g1, g2;
                clause_math(a0, a1, a2, xlA[c], xsA[c], zeta, C, g0, g1, g2);
                unsafeAtomicAdd(&gb[i0], -g0 * s0);   // fire-and-forget L2 atomic
                unsafeAtomicAdd(&gb[i1], -g1 * s1);
                unsafeAtomicAdd(&gb[i2], -g2 * s2);
                Cv[c]   = C;
                dxlv[c] = -alpha * (C - delta);
                dxsv[c] = -beta * (xsA[c] + eps) * (C - gamma);
            }
            const float4v cv  = {Cv[0], Cv[1], Cv[2], Cv[3]};
            const float4v lv  = {dxlv[0], dxlv[1], dxlv[2], dxlv[3]};
            const float4v svo = {dxsv[0], dxsv[1], dxsv[2], dxsv[3]};
            __builtin_nontemporal_store(cv,  (float4v*)(outC + base));
            __builtin_nontemporal_store(lv,  (float4v*)(outdxl + base));
            __builtin_nontemporal_store(svo, (float4v*)(outdxs + base));

            // rotate pipeline registers
            ia = ia2; ib = ib2; ic = ic2;
            sa = sa2; sb = sb2; sc = sc2;
            xl4 = xl42; xs4 = xs42;
        }
    } else {
        // ragged tail fallback (not hit for M%4==0 shapes)
        for (int m = mstart + tid; m < mend; m += 1024) {
            const size_t bm  = (size_t)b * M + m;
            const size_t bm3 = bm * 3;
            const int   i0 = idx[bm3 + 0], i1 = idx[bm3 + 1], i2 = idx[bm3 + 2];
            const float s0 = sign[bm3 + 0], s1 = sign[bm3 + 1], s2 = sign[bm3 + 2];
            const float a0 = sv[i0] * s0, a1 = sv[i1] * s1, a2 = sv[i2] * s2;
            const float xlv = xl[bm], xsv = xs[bm];
            float C, g0, g1, g2;
            clause_math(a0, a1, a2, xlv, xsv, zeta, C, g0, g1, g2);
            unsafeAtomicAdd(&gb[i0], -g0 * s0);
            unsafeAtomicAdd(&gb[i1], -g1 * s1);
            unsafeAtomicAdd(&gb[i2], -g2 * s2);
            outC[bm]   = C;
            outdxl[bm] = -alpha * (C - delta);
            outdxs[bm] = -beta * (xsv + eps) * (C - gamma);
        }
    }
}

__global__ __launch_bounds__(256) void zero_f4(float4v* __restrict__ p, int n4) {
    int i = blockIdx.x * blockDim.x + threadIdx.x;
    int stride = gridDim.x * blockDim.x;
    const float4v z = {0.f, 0.f, 0.f, 0.f};
    for (; i < n4; i += stride) p[i] = z;
}

// ---------- fallback path (round-1, global atomics) ----------
__global__ __launch_bounds__(256) void or_kernel(
    const float* __restrict__ v, const float* __restrict__ xl,
    const float* __restrict__ xs, const float* __restrict__ param,
    const float* __restrict__ sign, const int* __restrict__ idx,
    float* __restrict__ outC, float* __restrict__ gradv,
    float* __restrict__ outdxl, float* __restrict__ outdxs, int N, int M)
{
    const int m = blockIdx.x * blockDim.x + threadIdx.x;
    const int b = blockIdx.y;
    if (m >= M) return;
    const size_t bm = (size_t)b * M + m;
    const size_t bm3 = bm * 3;
    const int   i0 = idx[bm3 + 0], i1 = idx[bm3 + 1], i2 = idx[bm3 + 2];
    const float s0 = sign[bm3 + 0], s1 = sign[bm3 + 1], s2 = sign[bm3 + 2];
    const float* __restrict__ vb = v + (size_t)b * N;
    const float a0 = vb[i0] * s0, a1 = vb[i1] * s1, a2 = vb[i2] * s2;
    const float xlv = xl[bm], xsv = xs[bm];
    const float alpha = param[0], beta = param[1], gamma = param[2];
    const float delta = param[3], eps  = param[4], zeta  = param[5];

    float C, g0, g1, g2;
    clause_math(a0, a1, a2, xlv, xsv, zeta, C, g0, g1, g2);

    float* __restrict__ gb = gradv + (size_t)b * N;
    atomicAdd(&gb[i0], -g0 * s0);
    atomicAdd(&gb[i1], -g1 * s1);
    atomicAdd(&gb[i2], -g2 * s2);

    outC[bm]   = C;
    outdxl[bm] = -alpha * (C - delta);
    outdxs[bm] = -beta * (xsv + eps) * (C - gamma);
}

extern "C" void kernel_launch(void* const* d_in, const int* in_sizes, int n_in,
                              void* d_out, int out_size, void* d_ws, size_t ws_size,
                              hipStream_t stream) {
    const float* v     = (const float*)d_in[0];
    const float* xl    = (const float*)d_in[1];
    const float* xs    = (const float*)d_in[2];
    const float* param = (const float*)d_in[3];
    const float* sign  = (const float*)d_in[4];
    const int*   idx   = (const int*)d_in[5];

    const int B = 128;
    const int N = in_sizes[0] / B;   // 20000
    const int M = in_sizes[1] / B;   // 85400

    float* outC   = (float*)d_out;
    float* gradv  = outC   + (size_t)in_sizes[1];
    float* outdxl = gradv  + (size_t)in_sizes[0];
    float* outdxs = outdxl + (size_t)in_sizes[1];

    const size_t bn = (size_t)B * N;
    const int n4 = (int)(bn / 4);

    if (N <= NMAX && (bn % 4) == 0 && (M % 4) == 0) {
        // zero grad, then scatter with fire-and-forget f32 atomics (L2-resident)
        zero_f4<<<dim3(min(2048, (n4 + 255) / 256)), dim3(256), 0, stream>>>(
            (float4v*)gradv, n4);
        // chunk: multiple of 4 so every group's base is 16B-aligned
        const int chunk = (((M + BPB - 1) / BPB) + 3) & ~3;
        or_priv5<<<dim3(BPB * B), dim3(1024), 0, stream>>>(
            v, xl, xs, param, sign, idx, outC, outdxl, outdxs,
            gradv, N, M, B, chunk);
    } else {
        zero_f4<<<dim3((n4 + 255) / 256), dim3(256), 0, stream>>>((float4v*)gradv, n4);
        dim3 grid((M + 255) / 256, B);
        or_kernel<<<grid, dim3(256), 0, stream>>>(v, xl, xs, param, sign, idx,
                                                  outC, gradv, outdxl, outdxs, N, M);
    }
}

// Round 4
// 456.545 us; speedup vs baseline: 4.0180x; 4.0180x over previous
//
#include <hip/hip_runtime.h>

// B=128 trajectories, N=20000 vars, M=85400 clauses, K=3 literals/clause.
// Inputs: v(B*N) f32, xl(B*M) f32, xs(B*M) f32, param(6) f32,
//         input_sign(B*M*K) f32, input_idx(B*M*K) i32
// Outputs concat: C(B*M), grad_v(B*N), dxl(B*M), dxs(B*M)  -- all f32

#define NMAX 20000     // sv (80KB) + sg (80KB) = 160KB LDS -> 1 block/CU
#define BPB  2         // clause-chunks per batch element -> grid 256 = 1/CU

typedef int   int4v   __attribute__((ext_vector_type(4)));
typedef float float4v __attribute__((ext_vector_type(4)));

// 12B packed triples, 4B-aligned -> global_load_dwordx3 at 12B lane-stride
// (wave covers 768B in 12 lines: coalescing minimum; the old per-thread-48B
//  dwordx4 pattern touched EVERY line 3x -> 288 requests where 96 suffice)
struct alignas(4) I3 { int   x, y, z; };
struct alignas(4) F3 { float x, y, z; };

// one clause's register state -- static field names only (no runtime indexing)
struct Cl { int i0, i1, i2; float s0, s1, s2, xlv, xsv; };

__device__ __forceinline__ void clause_math(
    float a0, float a1, float a2, float xlv, float xsv, float zeta,
    float& C, float& g0, float& g1, float& g2)
{
    // top-2 with jax.lax.top_k tie semantics (first occurrence wins argmax)
    int k0; float m0, m1;
    if (a0 >= a1) {
        if (a0 >= a2) { k0 = 0; m0 = a0; m1 = fmaxf(a1, a2); }
        else          { k0 = 2; m0 = a2; m1 = fmaxf(a0, a1); }
    } else {
        if (a1 >= a2) { k0 = 1; m0 = a1; m1 = fmaxf(a0, a2); }
        else          { k0 = 2; m0 = a2; m1 = fmaxf(a0, a1); }
    }
    C = (1.f - m0) * 0.5f;
    const float T2 = (1.f - m1) * 0.5f;
    const float gl = xlv * xsv;
    const float rC = C * ((1.f + zeta * xlv) * (1.f - xsv));
    g0 = (k0 == 0 ? T2 : C) * gl + (k0 == 0 ? rC : 0.f);
    g1 = (k0 == 1 ? T2 : C) * gl + (k0 == 1 ? rC : 0.f);
    g2 = (k0 == 2 ? T2 : C) * gl + (k0 == 2 ? rC : 0.f);
}

// ---------- fast path: v + grad in LDS, wave-strided clauses, pinned prefetch ----------
__global__ __launch_bounds__(1024, 4) void or_priv6(
    const float* __restrict__ v,
    const float* __restrict__ xl,
    const float* __restrict__ xs,
    const float* __restrict__ param,
    const float* __restrict__ sign,
    const int*   __restrict__ idx,
    float* __restrict__ outC,
    float* __restrict__ outdxl,
    float* __restrict__ outdxs,
    float* __restrict__ partial,   // [BPB][B][N]
    int N, int M, int B, int chunk)
{
    __shared__ float sv[NMAX];   // v slice (gathers stay in LDS -- R1 lesson)
    __shared__ float sg[NMAX];   // grad accumulator (stays in LDS -- R3 lesson)

    // XCD swizzle: the BPB=2 blocks of each b land on one XCD (v-stage L2 reuse)
    const int id  = blockIdx.x;
    const int cpx = gridDim.x >> 3;
    const int cid = ((gridDim.x & 7) == 0) ? ((id & 7) * cpx + (id >> 3)) : id;
    const int b   = cid >> 1;              // BPB == 2
    const int j   = cid & 1;
    const int tid = threadIdx.x;

    // stage v slice (coalesced float4, cached) + zero grad
    {
        const float4v* __restrict__ v4 = (const float4v*)(v + (size_t)b * N);
        float4v* sv4 = (float4v*)sv;
        float4v* sg4 = (float4v*)sg;
        const int n4 = N >> 2;
        const float4v z = {0.f, 0.f, 0.f, 0.f};
        for (int i = tid; i < n4; i += 1024) {
            sv4[i] = v4[i];
            sg4[i] = z;
        }
        for (int i = (n4 << 2) + tid; i < N; i += 1024) {
            sv[i] = v[(size_t)b * N + i];
            sg[i] = 0.f;
        }
    }
    __syncthreads();

    const float alpha = param[0], beta = param[1], gamma = param[2];
    const float delta = param[3], eps  = param[4], zeta  = param[5];

    const int mstart = j * chunk;
    const int mend   = min(M, mstart + chunk);
    const size_t bM  = (size_t)b * M;

    const I3* __restrict__ ip = (const I3*)idx;
    const F3* __restrict__ sp = (const F3*)sign;

    // thread t owns clauses mstart+t, +1024, +2048, ... (wave-strided: every
    // load instruction is minimal-segment coalesced). 2 clauses per iteration,
    // 1-deep pinned prefetch.
    #define LOADCL(dst, mm) do {                         \
        const size_t _bm = bM + (size_t)(mm);            \
        const I3 _i = ip[_bm];                           \
        const F3 _s = sp[_bm];                           \
        (dst).i0 = _i.x; (dst).i1 = _i.y; (dst).i2 = _i.z; \
        (dst).s0 = _s.x; (dst).s1 = _s.y; (dst).s2 = _s.z; \
        (dst).xlv = xl[_bm]; (dst).xsv = xs[_bm];        \
    } while (0)

    #define PROCCL(src, mm) do {                                            \
        const size_t _bm = bM + (size_t)(mm);                               \
        const float _a0 = sv[(src).i0] * (src).s0;                          \
        const float _a1 = sv[(src).i1] * (src).s1;                          \
        const float _a2 = sv[(src).i2] * (src).s2;                          \
        float _C, _g0, _g1, _g2;                                            \
        clause_math(_a0, _a1, _a2, (src).xlv, (src).xsv, zeta,              \
                    _C, _g0, _g1, _g2);                                     \
        unsafeAtomicAdd(&sg[(src).i0], -_g0 * (src).s0);                    \
        unsafeAtomicAdd(&sg[(src).i1], -_g1 * (src).s1);                    \
        unsafeAtomicAdd(&sg[(src).i2], -_g2 * (src).s2);                    \
        __builtin_nontemporal_store(_C, outC + _bm);                        \
        __builtin_nontemporal_store(-alpha * (_C - delta), outdxl + _bm);   \
        __builtin_nontemporal_store(-beta * ((src).xsv + eps) * (_C - gamma), \
                                    outdxs + _bm);                          \
    } while (0)

    int m = mstart + tid;
    if (m < mend) {
        Cl A0, A1;
        // prologue: load pair (m, m+1024), clamped
        {
            const int c1 = (m + 1024 < mend) ? (m + 1024) : m;
            LOADCL(A0, m);
            LOADCL(A1, c1);
        }
        for (; m < mend; m += 2048) {
            // issue next pair's loads EARLY (clamped so always in-bounds)
            Cl B0, B1;
            {
                const int mn  = (m + 2048 < mend) ? (m + 2048) : m;
                const int mn1 = (mn + 1024 < mend) ? (mn + 1024) : mn;
                LOADCL(B0, mn);
                LOADCL(B1, mn1);
            }
            // pin: loads above stay above the compute (rule #18 / T14)
            __builtin_amdgcn_sched_barrier(0);

            PROCCL(A0, m);
            if (m + 1024 < mend) PROCCL(A1, m + 1024);

            A0 = B0; A1 = B1;
        }
    }
    #undef LOADCL
    #undef PROCCL

    __syncthreads();

    // flush grad accumulator to the per-(j,b) partial slab (cached stores:
    // reduce2 then hits L2/L3 instead of HBM)
    {
        float* __restrict__ pj = partial + ((size_t)j * B + b) * N;
        const float4v* sg4 = (const float4v*)sg;
        const int n4 = N >> 2;
        for (int i = tid; i < n4; i += 1024)
            ((float4v*)pj)[i] = sg4[i];
        for (int i = (n4 << 2) + tid; i < N; i += 1024) pj[i] = sg[i];
    }
}

__global__ __launch_bounds__(256) void reduce2(
    const float4v* __restrict__ p, float4v* __restrict__ out, int n4, int stride4)
{
    int i = blockIdx.x * 256 + threadIdx.x;
    const int gs = gridDim.x * 256;
    for (; i < n4; i += gs) {
        const float4v a = p[i];
        const float4v b = p[i + stride4];
        out[i] = a + b;
    }
}

// ---------- fallback path (round-1, global atomics) ----------
__global__ __launch_bounds__(256) void zero_f4(float4v* __restrict__ p, int n4) {
    int i = blockIdx.x * blockDim.x + threadIdx.x;
    int stride = gridDim.x * blockDim.x;
    const float4v z = {0.f, 0.f, 0.f, 0.f};
    for (; i < n4; i += stride) p[i] = z;
}

__global__ __launch_bounds__(256) void or_kernel(
    const float* __restrict__ v, const float* __restrict__ xl,
    const float* __restrict__ xs, const float* __restrict__ param,
    const float* __restrict__ sign, const int* __restrict__ idx,
    float* __restrict__ outC, float* __restrict__ gradv,
    float* __restrict__ outdxl, float* __restrict__ outdxs, int N, int M)
{
    const int m = blockIdx.x * blockDim.x + threadIdx.x;
    const int b = blockIdx.y;
    if (m >= M) return;
    const size_t bm = (size_t)b * M + m;
    const size_t bm3 = bm * 3;
    const int   i0 = idx[bm3 + 0], i1 = idx[bm3 + 1], i2 = idx[bm3 + 2];
    const float s0 = sign[bm3 + 0], s1 = sign[bm3 + 1], s2 = sign[bm3 + 2];
    const float* __restrict__ vb = v + (size_t)b * N;
    const float a0 = vb[i0] * s0, a1 = vb[i1] * s1, a2 = vb[i2] * s2;
    const float xlv = xl[bm], xsv = xs[bm];
    const float alpha = param[0], beta = param[1], gamma = param[2];
    const float delta = param[3], eps  = param[4], zeta  = param[5];

    float C, g0, g1, g2;
    clause_math(a0, a1, a2, xlv, xsv, zeta, C, g0, g1, g2);

    float* __restrict__ gb = gradv + (size_t)b * N;
    atomicAdd(&gb[i0], -g0 * s0);
    atomicAdd(&gb[i1], -g1 * s1);
    atomicAdd(&gb[i2], -g2 * s2);

    outC[bm]   = C;
    outdxl[bm] = -alpha * (C - delta);
    outdxs[bm] = -beta * (xsv + eps) * (C - gamma);
}

extern "C" void kernel_launch(void* const* d_in, const int* in_sizes, int n_in,
                              void* d_out, int out_size, void* d_ws, size_t ws_size,
                              hipStream_t stream) {
    const float* v     = (const float*)d_in[0];
    const float* xl    = (const float*)d_in[1];
    const float* xs    = (const float*)d_in[2];
    const float* param = (const float*)d_in[3];
    const float* sign  = (const float*)d_in[4];
    const int*   idx   = (const int*)d_in[5];

    const int B = 128;
    const int N = in_sizes[0] / B;   // 20000
    const int M = in_sizes[1] / B;   // 85400

    float* outC   = (float*)d_out;
    float* gradv  = outC   + (size_t)in_sizes[1];
    float* outdxl = gradv  + (size_t)in_sizes[0];
    float* outdxs = outdxl + (size_t)in_sizes[1];

    const size_t bn = (size_t)B * N;
    const size_t ws_need = (size_t)BPB * bn * sizeof(float);

    if (N <= NMAX && ws_size >= ws_need && (bn % 4) == 0) {
        float* partial = (float*)d_ws;
        const int chunk = (((M + BPB - 1) / BPB) + 3) & ~3;
        or_priv6<<<dim3(BPB * B), dim3(1024), 0, stream>>>(
            v, xl, xs, param, sign, idx, outC, outdxl, outdxs,
            (float*)partial, N, M, B, chunk);
        const int n4 = (int)(bn / 4);
        const int rblocks = min(2048, (n4 + 255) / 256);
        reduce2<<<dim3(rblocks), dim3(256), 0, stream>>>(
            (const float4v*)partial, (float4v*)gradv, n4, n4);
    } else {
        const int n4 = (int)(bn / 4);
        zero_f4<<<dim3((n4 + 255) / 256), dim3(256), 0, stream>>>((float4v*)gradv, n4);
        dim3 grid((M + 255) / 256, B);
        or_kernel<<<grid, dim3(256), 0, stream>>>(v, xl, xs, param, sign, idx,
                                                  outC, gradv, outdxl, outdxs, N, M);
    }
}